// Round 1
// baseline (92.430 us; speedup 1.0000x reference)
//
#include <hip/hip_runtime.h>

// ImpSentenceModel: emb = table[tokens]; out[b,seg,:] = sum over tokens with segment_ids==seg.
// segment_ids sorted per row -> each (b,seg) is a contiguous token range [start,end).
// One block per (b,seg): binary-search range, 8x 32-lane groups sum stripes, LDS-reduce, one write.

#define D 128
#define MAXL 64

__device__ __forceinline__ int lower_bound_i32(const int* __restrict__ s, int n, int v) {
    int lo = 0, hi = n;
    while (lo < hi) {
        int mid = (lo + hi) >> 1;
        if (s[mid] < v) lo = mid + 1; else hi = mid;
    }
    return lo;
}

__global__ __launch_bounds__(256, 8) void seg_embed_sum_kernel(
    const int* __restrict__ tokens,   // [B, T]
    const int* __restrict__ segs,     // [B, T], sorted per row, values in [0, MAXL)
    const float* __restrict__ table,  // [VOCAB, D]
    float* __restrict__ out,          // [B, MAXL, D]
    int T) {
    const int seg   = blockIdx.x;     // 0..MAXL-1
    const int b     = blockIdx.y;     // 0..B-1
    const int tid   = threadIdx.x;    // 0..255
    const int group = tid >> 5;       // 0..7 (half-wave groups)
    const int lane  = tid & 31;       // 0..31

    // Uniform binary searches: all threads same addresses -> broadcast loads.
    const int* srow = segs + (size_t)b * T;
    const int start = lower_bound_i32(srow, T, seg);
    const int end   = lower_bound_i32(srow, T, seg + 1);
    const int count = end - start;

    const int* trow = tokens + (size_t)b * T + start;

    // Contiguous stripe per group (coalesced id loads within a group).
    const int per    = (count + 7) >> 3;           // ceil(count/8)
    const int gstart = group * per;
    const int gend   = min(count, gstart + per);

    float4 acc = make_float4(0.f, 0.f, 0.f, 0.f);

    for (int base = gstart; base < gend; base += 32) {
        const int n = min(32, gend - base);
        int tok = 0;
        if (lane < n) tok = trow[base + lane];      // coalesced 128B id load per group
        #pragma unroll 4
        for (int j = 0; j < n; ++j) {
            const int t = __shfl(tok, j, 32);       // broadcast token id within half-wave
            // 32 lanes x float4 = one coalesced 512B row read
            const float4 v = *reinterpret_cast<const float4*>(
                table + (size_t)t * D + lane * 4);
            acc.x += v.x; acc.y += v.y; acc.z += v.z; acc.w += v.w;
        }
    }

    // LDS reduction: 8 group partials -> 1
    __shared__ float red[8][D];
    *reinterpret_cast<float4*>(&red[group][lane * 4]) = acc;
    __syncthreads();

    if (tid < 32) {
        float4 s = make_float4(0.f, 0.f, 0.f, 0.f);
        #pragma unroll
        for (int g = 0; g < 8; ++g) {
            const float4 v = *reinterpret_cast<const float4*>(&red[g][tid * 4]);
            s.x += v.x; s.y += v.y; s.z += v.z; s.w += v.w;
        }
        // exactly-once write; empty segments write zeros (also handles 0xAA poison)
        *reinterpret_cast<float4*>(out + ((size_t)b * MAXL + seg) * D + tid * 4) = s;
    }
}

extern "C" void kernel_launch(void* const* d_in, const int* in_sizes, int n_in,
                              void* d_out, int out_size, void* d_ws, size_t ws_size,
                              hipStream_t stream) {
    const int* tokens  = (const int*)d_in[0];     // paragraph_variable [B,T] int32
    const int* segs    = (const int*)d_in[1];     // segment_ids [B,T] int32 (sorted per row)
    const float* table = (const float*)d_in[3];   // embedding_table [VOCAB, D] f32
    float* out         = (float*)d_out;           // [B, MAXL, D] f32

    const int B = out_size / (MAXL * D);          // 32
    const int T = in_sizes[0] / B;                // 8192

    dim3 grid(MAXL, B);                           // 2048 blocks = 8/CU * 256 CU
    seg_embed_sum_kernel<<<grid, 256, 0, stream>>>(tokens, segs, table, out, T);
}

// Round 2
// 89.472 us; speedup vs baseline: 1.0331x; 1.0331x over previous
//
#include <hip/hip_runtime.h>

// ImpSentenceModel: emb = table[tokens]; out[b,seg,:] = sum over tokens with segment_ids==seg.
// segment_ids sorted per row -> each (b,seg) is a contiguous token range [start,end).
// One block per (b,seg): wave-parallel 3-probe lower_bound (vs 13-step serial),
// 8x 32-lane groups gather+sum contiguous stripes with 4-deep load ILP, LDS-reduce, one write.

#define D 128
#define MAXL 64

// Serial fallback (generic T)
__device__ __forceinline__ int lower_bound_serial(const int* __restrict__ s, int n, int v) {
    int lo = 0, hi = n;
    while (lo < hi) {
        int mid = (lo + hi) >> 1;
        if (s[mid] < v) lo = mid + 1; else hi = mid;
    }
    return lo;
}

// Wave-parallel lower_bound over n==8192 (=64*128): 3 dependent loads.
// Returns first idx in [0,8192] with s[idx] >= v. Result is wave-uniform.
__device__ __forceinline__ int wave_lower_bound_8192(const int* __restrict__ s, int v, int lane) {
    // Level 1: 64 probes at stride 128 (covers 0..8064)
    int x1 = s[lane << 7];
    unsigned long long m1 = __ballot(x1 < v);
    int c1 = __popcll(m1);                    // prefix count; lb in ((c1-1)*128, c1*128]
    if (c1 == 0) return 0;                    // s[0] >= v
    const int lo = ((c1 - 1) << 7) + 1;       // candidates [lo, lo+127], probes stay <= 8191
    // Level 2: 64 probes at stride 2 (covers lo..lo+126)
    int x2 = s[lo + (lane << 1)];
    unsigned long long m2 = __ballot(x2 < v);
    int c2 = __popcll(m2);
    if (c2 == 64) return lo + 127;            // all < v -> lb = c1*128
    if (c2 == 0)  return lo;                  // s[lo] >= v, s[lo-1] < v
    // Level 3: one scalar probe resolves the 2-candidate window
    const int a = lo + (c2 << 1) - 1;
    return (s[a] < v) ? a + 1 : a;
}

__global__ __launch_bounds__(256, 8) void seg_embed_sum_kernel(
    const int* __restrict__ tokens,   // [B, T]
    const int* __restrict__ segs,     // [B, T], sorted per row, values in [0, MAXL)
    const float* __restrict__ table,  // [VOCAB, D]
    float* __restrict__ out,          // [B, MAXL, D]
    int T) {
    const int seg   = blockIdx.x;     // 0..MAXL-1
    const int b     = blockIdx.y;     // 0..B-1
    const int tid   = threadIdx.x;    // 0..255
    const int group = tid >> 5;       // 0..7 (half-wave groups)
    const int lane  = tid & 31;       // 0..31

    const int* srow = segs + (size_t)b * T;

    __shared__ int sbounds[2];
    if (T == 8192) {
        const int wave = tid >> 6;            // 0..3
        const int wl   = tid & 63;
        // waves 0,2 find start (>= seg); waves 1,3 find end (>= seg+1)
        const int lb = wave_lower_bound_8192(srow, seg + (wave & 1), wl);
        if (wl == 0) sbounds[wave & 1] = lb;  // duplicate writes carry identical values
    } else {
        if (tid < 2) sbounds[tid] = lower_bound_serial(srow, T, seg + tid);
    }
    __syncthreads();

    const int start = sbounds[0];
    const int end   = sbounds[1];
    const int count = end - start;

    const int* trow = tokens + (size_t)b * T + start;

    // Contiguous stripe per group (coalesced id loads within a group).
    const int per    = (count + 7) >> 3;      // ceil(count/8)
    const int gstart = group * per;
    const int gend   = min(count, gstart + per);

    float4 acc0 = make_float4(0.f, 0.f, 0.f, 0.f);
    float4 acc1 = make_float4(0.f, 0.f, 0.f, 0.f);

    for (int base = gstart; base < gend; base += 32) {
        const int n = min(32, gend - base);
        int tok = 0;
        if (lane < n) tok = trow[base + lane];          // coalesced 128B id load per group
        int j = 0;
        for (; j + 4 <= n; j += 4) {                    // 4 independent 512B row-gathers in flight
            const int t0 = __shfl(tok, j,     32);
            const int t1 = __shfl(tok, j + 1, 32);
            const int t2 = __shfl(tok, j + 2, 32);
            const int t3 = __shfl(tok, j + 3, 32);
            const float4 v0 = *reinterpret_cast<const float4*>(table + (size_t)t0 * D + lane * 4);
            const float4 v1 = *reinterpret_cast<const float4*>(table + (size_t)t1 * D + lane * 4);
            const float4 v2 = *reinterpret_cast<const float4*>(table + (size_t)t2 * D + lane * 4);
            const float4 v3 = *reinterpret_cast<const float4*>(table + (size_t)t3 * D + lane * 4);
            acc0.x += v0.x; acc0.y += v0.y; acc0.z += v0.z; acc0.w += v0.w;
            acc1.x += v1.x; acc1.y += v1.y; acc1.z += v1.z; acc1.w += v1.w;
            acc0.x += v2.x; acc0.y += v2.y; acc0.z += v2.z; acc0.w += v2.w;
            acc1.x += v3.x; acc1.y += v3.y; acc1.z += v3.z; acc1.w += v3.w;
        }
        for (; j < n; ++j) {
            const int t = __shfl(tok, j, 32);
            const float4 v = *reinterpret_cast<const float4*>(table + (size_t)t * D + lane * 4);
            acc0.x += v.x; acc0.y += v.y; acc0.z += v.z; acc0.w += v.w;
        }
    }
    acc0.x += acc1.x; acc0.y += acc1.y; acc0.z += acc1.z; acc0.w += acc1.w;

    // LDS reduction: 8 group partials -> 1
    __shared__ float red[8][D];
    *reinterpret_cast<float4*>(&red[group][lane * 4]) = acc0;
    __syncthreads();

    if (tid < 32) {
        float4 s = make_float4(0.f, 0.f, 0.f, 0.f);
        #pragma unroll
        for (int g = 0; g < 8; ++g) {
            const float4 v = *reinterpret_cast<const float4*>(&red[g][tid * 4]);
            s.x += v.x; s.y += v.y; s.z += v.z; s.w += v.w;
        }
        // exactly-once write; empty segments write zeros (also clears 0xAA poison)
        *reinterpret_cast<float4*>(out + ((size_t)b * MAXL + seg) * D + tid * 4) = s;
    }
}

extern "C" void kernel_launch(void* const* d_in, const int* in_sizes, int n_in,
                              void* d_out, int out_size, void* d_ws, size_t ws_size,
                              hipStream_t stream) {
    const int* tokens  = (const int*)d_in[0];     // paragraph_variable [B,T] int32
    const int* segs    = (const int*)d_in[1];     // segment_ids [B,T] int32 (sorted per row)
    const float* table = (const float*)d_in[3];   // embedding_table [VOCAB, D] f32
    float* out         = (float*)d_out;           // [B, MAXL, D] f32

    const int B = out_size / (MAXL * D);          // 32
    const int T = in_sizes[0] / B;                // 8192

    dim3 grid(MAXL, B);                           // 2048 blocks = 8/CU * 256 CU
    seg_embed_sum_kernel<<<grid, 256, 0, stream>>>(tokens, segs, table, out, T);
}